// Round 2
// baseline (83.509 us; speedup 1.0000x reference)
//
#include <hip/hip_runtime.h>
#include <hip/hip_bf16.h>

#define ALPHA  0.2f
#define L2E    1.4426950408889634f

typedef __attribute__((ext_vector_type(8))) short  short8;
typedef __attribute__((ext_vector_type(4))) float  f32x4;
typedef unsigned short u16;

__device__ __forceinline__ u16 f2bf(float f) {
    union { float f; unsigned int u; } v; v.f = f;
    unsigned int r = (v.u + 0x7FFFu + ((v.u >> 16) & 1u)) >> 16;   // RNE
    return (u16)r;
}
__device__ __forceinline__ float lrelu(float x) { return fmaxf(x, ALPHA * x); }

// ---------------- prep1: W -> wbt (bf16, transposed [c][k]); w1 = W@a1, w2 = W@a2
__global__ void prep1(const float* __restrict__ W, const float* __restrict__ a1,
                      const float* __restrict__ a2, u16* __restrict__ wbt,
                      float* __restrict__ w1, float* __restrict__ w2) {
    int b = blockIdx.x;
    if (b < 64) {
        int t  = threadIdx.x;
        int kk = t >> 6;
        int c4 = (t & 63) * 4;
        int k  = b * 4 + kk;
        float4 w = *(const float4*)(W + (size_t)k * 256 + c4);
        wbt[(c4 + 0) * 256 + k] = f2bf(w.x);
        wbt[(c4 + 1) * 256 + k] = f2bf(w.y);
        wbt[(c4 + 2) * 256 + k] = f2bf(w.z);
        wbt[(c4 + 3) * 256 + k] = f2bf(w.w);
    } else {
        int bb = b - 64;                       // 0..3
        int wv = threadIdx.x >> 6, lane = threadIdx.x & 63;
        for (int kk = 0; kk < 16; ++kk) {
            int k = bb * 64 + wv * 16 + kk;
            float4 wv4 = *(const float4*)(W + (size_t)k * 256 + 4 * lane);
            float4 a14 = *(const float4*)(a1 + 4 * lane);
            float4 a24 = *(const float4*)(a2 + 4 * lane);
            float d1 = wv4.x*a14.x + wv4.y*a14.y + wv4.z*a14.z + wv4.w*a14.w;
            float d2 = wv4.x*a24.x + wv4.y*a24.y + wv4.z*a24.z + wv4.w*a24.w;
            #pragma unroll
            for (int off = 32; off; off >>= 1) {
                d1 += __shfl_xor(d1, off);
                d2 += __shfl_xor(d2, off);
            }
            if (lane == 0) { w1[k] = d1; w2[k] = d2; }
        }
    }
}

// ---------------- prep2: gw1 = gamma*w1, gw2 = gamma*w2, scal = {sgw1, sgw2, bw1, bw2}
__global__ void prep2(const float* __restrict__ gamma, const float* __restrict__ beta,
                      const float* __restrict__ w1, const float* __restrict__ w2,
                      float* __restrict__ gw1, float* __restrict__ gw2,
                      float* __restrict__ scal) {
    int t = threadIdx.x;                        // 256 threads
    float w1v = w1[t], w2v = w2[t], g = gamma[t], bt = beta[t];
    float v0 = g * w1v, v1 = g * w2v;
    gw1[t] = v0; gw2[t] = v1;
    float v2 = bt * w1v, v3 = bt * w2v;
    #pragma unroll
    for (int off = 32; off; off >>= 1) {
        v0 += __shfl_xor(v0, off); v1 += __shfl_xor(v1, off);
        v2 += __shfl_xor(v2, off); v3 += __shfl_xor(v3, off);
    }
    __shared__ float red[4][4];
    int wv = t >> 6, lane = t & 63;
    if (lane == 0) { red[wv][0] = v0; red[wv][1] = v1; red[wv][2] = v2; red[wv][3] = v3; }
    __syncthreads();
    if (t == 0) {
        scal[0] = red[0][0] + red[1][0] + red[2][0] + red[3][0];
        scal[1] = red[0][1] + red[1][1] + red[2][1] + red[3][1];
        scal[2] = red[0][2] + red[1][2] + red[2][2] + red[3][2];
        scal[3] = red[0][3] + red[1][3] + red[2][3] + red[3][3];
    }
}

// Swizzled 256x256 bf16 tile: element (r,c) at r*256 + (((c>>3)^(r&7))<<3) + (c&7)
struct SMem {
    u16   xb[256 * 256];      // 128 KB: x (LN'ed) then hT
    u16   st[8192];           // 16 KB: 2 x 8KB W-tile double buffer [c 128][k 32] rows of 64B
    float s1[256], s2[256], mrow[256], linv[256];
    float s2max;
};

__device__ __forceinline__ void stageW(u16* stbuf, const u16* __restrict__ wbt,
                                       int half, int ks, int wv, int lane) {
    int slot = wv * 64 + lane;                 // 0..511, 16B each
    int cl = slot >> 2, sq = slot & 3;
    const u16* src = wbt + (((half << 7) + cl) * 256 + ks * 32 + ((sq ^ ((cl >> 1) & 3)) << 3));
    u16* dst = stbuf + wv * 512;               // wave-uniform base; lane*16B implicit
    __builtin_amdgcn_global_load_lds((const __attribute__((address_space(1))) void*)src,
                                     (__attribute__((address_space(3))) void*)dst, 16, 0, 0);
}

__global__ __launch_bounds__(512, 2)
void gat_fused(const int* __restrict__ item_seq, const float* __restrict__ emb,
               const float* __restrict__ pos, const float* __restrict__ gamma,
               const float* __restrict__ beta, const u16* __restrict__ wbt,
               const float* __restrict__ gw1, const float* __restrict__ gw2,
               const float* __restrict__ scal, float* __restrict__ out)
{
    __shared__ SMem sm;
    const int b    = blockIdx.x;
    const int tid  = threadIdx.x;
    const int lane = tid & 63;
    const int wv   = tid >> 6;
    const int g    = lane >> 4;
    const int li   = lane & 15;

    // ---------------- Phase A: gather + LN + s1/s2, thread-per-half-row ----
    {
        int r = tid >> 1, hs = tid & 1;
        int iw = item_seq[(size_t)b * 256 + r];
        const float4* ep  = (const float4*)(emb + (size_t)iw * 256 + hs * 128);
        const float4* pp  = (const float4*)(pos + (size_t)r  * 256 + hs * 128);
        const float4* g1p = (const float4*)(gw1 + hs * 128);
        const float4* g2p = (const float4*)(gw2 + hs * 128);
        float4 xr[32];
        float s = 0.f, q = 0.f, d1 = 0.f, d2 = 0.f;
        #pragma unroll
        for (int m = 0; m < 32; ++m) {
            float4 e = ep[m], p = pp[m];
            float4 v; v.x = e.x + p.x; v.y = e.y + p.y; v.z = e.z + p.z; v.w = e.w + p.w;
            xr[m] = v;
            s += v.x + v.y + v.z + v.w;
            q += v.x*v.x + v.y*v.y + v.z*v.z + v.w*v.w;
            float4 w1v = g1p[m], w2v = g2p[m];
            d1 += v.x*w1v.x + v.y*w1v.y + v.z*w1v.z + v.w*w1v.w;
            d2 += v.x*w2v.x + v.y*w2v.y + v.z*w2v.z + v.w*w2v.w;
        }
        s  += __shfl_xor(s, 1);  q  += __shfl_xor(q, 1);
        d1 += __shfl_xor(d1, 1); d2 += __shfl_xor(d2, 1);
        float mu  = s * (1.0f / 256.0f);
        float var = q * (1.0f / 256.0f) - mu * mu;
        float rs  = rsqrtf(var + 1e-12f);
        float4 sc = *(const float4*)scal;      // sgw1, sgw2, bw1, bw2
        if (hs == 0) sm.s1[r] = rs * (d1 - mu * sc.x) + sc.z;
        else         sm.s2[r] = rs * (d2 - mu * sc.y) + sc.w;
        const float4* gp = (const float4*)(gamma + hs * 128);
        const float4* bp = (const float4*)(beta  + hs * 128);
        #pragma unroll
        for (int mp = 0; mp < 16; ++mp) {
            float4 va = xr[2*mp], vb = xr[2*mp+1];
            float4 ga = gp[2*mp], gb = gp[2*mp+1];
            float4 ba = bp[2*mp], bb = bp[2*mp+1];
            union { u16 us[8]; short8 v8; } pk;
            pk.us[0] = f2bf((va.x - mu) * rs * ga.x + ba.x);
            pk.us[1] = f2bf((va.y - mu) * rs * ga.y + ba.y);
            pk.us[2] = f2bf((va.z - mu) * rs * ga.z + ba.z);
            pk.us[3] = f2bf((va.w - mu) * rs * ga.w + ba.w);
            pk.us[4] = f2bf((vb.x - mu) * rs * gb.x + bb.x);
            pk.us[5] = f2bf((vb.y - mu) * rs * gb.y + bb.y);
            pk.us[6] = f2bf((vb.z - mu) * rs * gb.z + bb.z);
            pk.us[7] = f2bf((vb.w - mu) * rs * gb.w + bb.w);
            int ch = hs * 16 + mp;
            *(short8*)&sm.xb[r * 256 + ((ch ^ (r & 7)) << 3)] = pk.v8;
        }
    }
    // prologue stage for GEMM1 (no barrier needed before issuing; st untouched above)
    stageW(&sm.st[0], wbt, 0, 0, wv, lane);

    // ---------------- Phase C: h = x @ W (MFMA), dbuf W staging -------------
    const int ig = wv >> 1;   // m-group: rows ig*64
    const int ng = wv & 1;    // n-group within half: cols ng*64
    unsigned int stash[32];
    f32x4 acc[4][4];
    int cur = 0;

    for (int half = 0; half < 2; ++half) {
        #pragma unroll
        for (int mt = 0; mt < 4; ++mt)
            #pragma unroll
            for (int nt = 0; nt < 4; ++nt)
                acc[mt][nt] = (f32x4){0.f, 0.f, 0.f, 0.f};

        for (int ks = 0; ks < 8; ++ks) {
            __syncthreads();                    // staged buf[cur] visible (first = A->C barrier)
            int nks = ks + 1, nh = half;
            if (nks == 8) { nks = 0; nh = half + 1; }
            if (nh < 2) stageW(&sm.st[(cur ^ 1) * 4096], wbt, nh, nks, wv, lane);

            const u16* stb = &sm.st[cur * 4096];
            short8 bfr[4];
            #pragma unroll
            for (int nt = 0; nt < 4; ++nt) {
                int cl = ng * 64 + nt * 16 + li;
                bfr[nt] = *(const short8*)&stb[cl * 32 + ((g ^ ((cl >> 1) & 3)) << 3)];
            }
            #pragma unroll
            for (int mt = 0; mt < 4; ++mt) {
                int r  = ig * 64 + mt * 16 + li;
                int kc = ks * 4 + g;
                short8 af = *(const short8*)&sm.xb[r * 256 + ((kc ^ (r & 7)) << 3)];
                #pragma unroll
                for (int nt = 0; nt < 4; ++nt)
                    acc[mt][nt] = __builtin_amdgcn_mfma_f32_16x16x32_bf16(
                        af, bfr[nt], acc[mt][nt], 0, 0, 0);
            }
            cur ^= 1;
        }
        if (half == 0) {
            #pragma unroll
            for (int mt = 0; mt < 4; ++mt)
                #pragma unroll
                for (int nt = 0; nt < 4; ++nt) {
                    int t = (mt * 4 + nt) * 2;
                    stash[t]   = (unsigned)f2bf(acc[mt][nt][0]) | ((unsigned)f2bf(acc[mt][nt][1]) << 16);
                    stash[t+1] = (unsigned)f2bf(acc[mt][nt][2]) | ((unsigned)f2bf(acc[mt][nt][3]) << 16);
                }
        }
    }
    __syncthreads();   // all xb (=x) reads complete before overwrite with hT

    // ---------------- write hT into xb (swizzled); wave0 also does s2max ----
    #pragma unroll
    for (int half = 0; half < 2; ++half)
        #pragma unroll
        for (int mt = 0; mt < 4; ++mt)
            #pragma unroll
            for (int nt = 0; nt < 4; ++nt) {
                int c  = half * 128 + ng * 64 + nt * 16 + li;
                int i0 = ig * 64 + mt * 16 + 4 * g;
                unsigned int lo, hi;
                if (half == 0) {
                    int t = (mt * 4 + nt) * 2;
                    lo = stash[t]; hi = stash[t + 1];
                } else {
                    lo = (unsigned)f2bf(acc[mt][nt][0]) | ((unsigned)f2bf(acc[mt][nt][1]) << 16);
                    hi = (unsigned)f2bf(acc[mt][nt][2]) | ((unsigned)f2bf(acc[mt][nt][3]) << 16);
                }
                uint2 v; v.x = lo; v.y = hi;
                *(uint2*)&sm.xb[c * 256 + (((i0 >> 3) ^ (c & 7)) << 3) + (i0 & 7)] = v;
            }
    if (wv == 0) {
        float m0 = fmaxf(fmaxf(sm.s2[lane], sm.s2[lane + 64]),
                         fmaxf(sm.s2[lane + 128], sm.s2[lane + 192]));
        #pragma unroll
        for (int off = 32; off; off >>= 1) m0 = fmaxf(m0, __shfl_xor(m0, off));
        if (lane == 0) sm.s2max = m0;
    }
    __syncthreads();

    // ---------------- Phase E: row max (exact) + 1/l_i ----------------------
    {
        int i = tid >> 1, jh = tid & 1;
        float s1v = sm.s1[i];
        float mi  = lrelu(s1v + sm.s2max);
        float sum = 0.f;
        for (int j = jh * 128; j < jh * 128 + 128; ++j) {
            float e = lrelu(s1v + sm.s2[j]);
            sum += __builtin_amdgcn_exp2f((e - mi) * L2E);
        }
        sum += __shfl_xor(sum, 1);
        if (jh == 0) { sm.mrow[i] = mi; sm.linv[i] = 1.0f / sum; }
    }
    __syncthreads();

    // ---------------- Phase F: out = P @ h (MFMA), P built in-register ------
    {
        const int ig2 = wv >> 1;
        const int ng2 = wv & 1;
        f32x4 oacc[4][8];
        #pragma unroll
        for (int mt = 0; mt < 4; ++mt)
            #pragma unroll
            for (int nt = 0; nt < 8; ++nt)
                oacc[mt][nt] = (f32x4){0.f, 0.f, 0.f, 0.f};

        float s1v[4], mv[4], lv[4];
        #pragma unroll
        for (int mt = 0; mt < 4; ++mt) {
            int i = ig2 * 64 + mt * 16 + li;
            s1v[mt] = sm.s1[i]; mv[mt] = sm.mrow[i]; lv[mt] = sm.linv[i];
        }

        for (int js = 0; js < 8; ++js) {
            float s2l[8];
            #pragma unroll
            for (int jj = 0; jj < 8; ++jj) s2l[jj] = sm.s2[js * 32 + g * 8 + jj];

            short8 pfr[4];
            #pragma unroll
            for (int mt = 0; mt < 4; ++mt) {
                union { unsigned int u[4]; short8 s; } pk;
                #pragma unroll
                for (int q2 = 0; q2 < 4; ++q2) {
                    float e0 = lrelu(s1v[mt] + s2l[2 * q2]);
                    float e1 = lrelu(s1v[mt] + s2l[2 * q2 + 1]);
                    float p0 = __builtin_amdgcn_exp2f((e0 - mv[mt]) * L2E) * lv[mt];
                    float p1 = __builtin_amdgcn_exp2f((e1 - mv[mt]) * L2E) * lv[mt];
                    pk.u[q2] = (unsigned int)f2bf(p0) | ((unsigned int)f2bf(p1) << 16);
                }
                pfr[mt] = pk.s;
            }
            #pragma unroll
            for (int nt = 0; nt < 8; ++nt) {
                int c  = ng2 * 128 + nt * 16 + li;
                int kc = js * 4 + g;
                short8 vf = *(const short8*)&sm.xb[c * 256 + ((kc ^ (c & 7)) << 3)];
                #pragma unroll
                for (int mt = 0; mt < 4; ++mt)
                    oacc[mt][nt] = __builtin_amdgcn_mfma_f32_16x16x32_bf16(
                        pfr[mt], vf, oacc[mt][nt], 0, 0, 0);
            }
        }

        size_t ob = (size_t)b * (256 * 256);
        #pragma unroll
        for (int mt = 0; mt < 4; ++mt)
            #pragma unroll
            for (int nt = 0; nt < 8; ++nt) {
                int c  = ng2 * 128 + nt * 16 + li;
                int i0 = ig2 * 64 + mt * 16 + 4 * g;
                #pragma unroll
                for (int q2 = 0; q2 < 4; ++q2)
                    out[ob + (size_t)(i0 + q2) * 256 + c] = oacc[mt][nt][q2];
            }
    }
}

extern "C" void kernel_launch(void* const* d_in, const int* in_sizes, int n_in,
                              void* d_out, int out_size, void* d_ws, size_t ws_size,
                              hipStream_t stream) {
    (void)in_sizes; (void)n_in; (void)out_size; (void)ws_size;
    const int*   seq   = (const int*)d_in[0];
    const float* emb   = (const float*)d_in[1];
    const float* pos   = (const float*)d_in[2];
    const float* W     = (const float*)d_in[3];
    const float* a1    = (const float*)d_in[4];
    const float* a2    = (const float*)d_in[5];
    const float* gamma = (const float*)d_in[6];
    const float* beta  = (const float*)d_in[7];

    char* ws = (char*)d_ws;
    u16*   wbt  = (u16*)ws;                    // 131072 B
    float* w1   = (float*)(ws + 131072);
    float* w2   = (float*)(ws + 132096);
    float* gw1f = (float*)(ws + 133120);
    float* gw2f = (float*)(ws + 134144);
    float* scal = (float*)(ws + 135168);       // 16 B

    hipLaunchKernelGGL(prep1, dim3(68), dim3(256), 0, stream, W, a1, a2, wbt, w1, w2);
    hipLaunchKernelGGL(prep2, dim3(1), dim3(256), 0, stream, gamma, beta, w1, w2, gw1f, gw2f, scal);
    hipLaunchKernelGGL(gat_fused, dim3(256), dim3(512), 0, stream,
                       seq, emb, pos, gamma, beta, wbt, gw1f, gw2f, scal, (float*)d_out);
}